// Round 7
// baseline (398.494 us; speedup 1.0000x reference)
//
#include <hip/hip_runtime.h>
#include <stdint.h>

// Problem constants: B=32, S=2048, K=512, V=512, H=256
#define Bb 32
#define Ss 2048
#define Kk 512
#define Vv 512
#define Hh 256

#define OUTP (Bb * Vv) // offset of p within d_out (out [1,B,V] then p [B,S])

// ws layout (bytes):
//   [0,       32768)   hq[B][H] fp32 (= q@Wq^T + bq + bk)
//   [32768,  294912)   Wk bf16, frag-major: [stage32][grp=lg][h][8]
//   [294912, 557056)   w[B][S] fp32 (unnormalized exp(logit))
#define WS_HQ 0
#define WS_WKB 32768
#define WS_LOGIT 294912

typedef float floatx4 __attribute__((ext_vector_type(4)));
typedef __bf16 bf16x8 __attribute__((ext_vector_type(8)));

__device__ __forceinline__ uint32_t bfround(float f) {
  uint32_t u = __float_as_uint(f);
  return (u + 0x7fffu + ((u >> 16) & 1u)) >> 16;
}
__device__ __forceinline__ uint32_t packbf(float lo, float hi) {
  return bfround(lo) | (bfround(hi) << 16);
}

// ---------------------------------------------------------------------------
// prep (merged): blocks [0,128): retile Wk fp32 -> bf16 frag-major (BK=32).
//                blocks [128,384): hq[b][h] = q[b]·Wq[h] + bq[h] + bk[h]
//                block 384: zero the out-section of d_out (gemm atomics land there)
__global__ void prep(const float* __restrict__ q, const float* __restrict__ Wq,
                     const float* __restrict__ bq, const float* __restrict__ bk,
                     const float* __restrict__ Wk, uint16_t* __restrict__ wkb,
                     float* __restrict__ hq, float* __restrict__ dout) {
  __shared__ float red[256];
  const int bx = blockIdx.x;
  const int t = threadIdx.x;
  if (bx < 128) {
    const int i = (bx * 256 + t) * 4; // 4 consecutive k of one h row
    float4 w = *(const float4*)(Wk + i);
    const int h = i >> 9;
    const int k = i & 511;
    const int stage = k >> 5;      // 16 stages of K=32
    const int grp = (k & 31) >> 3; // lg group 0..3
    const int j = k & 7;           // 0 or 4 here
    uint2 pk;
    pk.x = packbf(w.x, w.y);
    pk.y = packbf(w.z, w.w);
    *(uint2*)(wkb + stage * 8192 + (grp * 256 + h) * 8 + j) = pk;
  } else if (bx < 384) {
    const int idx = bx - 128; // 0..255
    const int b = idx >> 3;
    const int hc = idx & 7;
    const int h_in = t & 31;
    const int kp = t >> 5; // 8-way K split
    const int h = hc * 32 + h_in;
    const float4* qp = (const float4*)(q + b * Kk + kp * 64);
    const float4* wp = (const float4*)(Wq + h * Kk + kp * 64);
    float acc = 0.f;
#pragma unroll
    for (int i = 0; i < 16; ++i) {
      float4 qa = qp[i], wa = wp[i];
      acc = fmaf(qa.x, wa.x, acc);
      acc = fmaf(qa.y, wa.y, acc);
      acc = fmaf(qa.z, wa.z, acc);
      acc = fmaf(qa.w, wa.w, acc);
    }
    red[t] = acc;
    __syncthreads();
    if (t < 32) {
      float s = 0.f;
#pragma unroll
      for (int kp2 = 0; kp2 < 8; ++kp2) s += red[kp2 * 32 + t];
      const int hh = hc * 32 + t;
      hq[b * Hh + hh] = s + bq[hh] + bk[hh];
    }
  } else {
    // zero out-section: Bb*Vv = 16384 floats = 4096 float4
    float4 z = {0.f, 0.f, 0.f, 0.f};
    float4* o = (float4*)dout + t;
#pragma unroll
    for (int i = 0; i < 16; ++i) o[i * 256] = z;
  }
}

// ---------------------------------------------------------------------------
// Main GEMM+tanh+logit+exp + fused weighted-V accumulation.
// Block (sc, b): 64 consecutive s for one batch b. BM=64, BN=256, BK=32.
// BARRIER-FREE K-loop: no LDS staging at all.
//   - A: each wave loads its fragments straight from global (fp32 -> packbf ->
//     bf16x8). Per fragment-instr the wave touches 16 rows x 128B contiguous
//     (32 fully-used 64B lines). Per-stage block working set = 8KB -> waves
//     2..4 hit L1/L2; HBM k-traffic stays ~134MB.
//   - B: straight from frag-major wkb (L2-resident, 256KB/block, read once).
//   - Compiler software-pipelines the 12 loads/stage across the unrolled loop;
//     no vmcnt(0) drains anywhere in the loop, waves never convoy.
//   - Epilogue (one barrier pair): cross-wave logit reduce, w = exp(logit)
//     (|logit| <= 25.6, fp32-safe, max-sub redundant), then fused
//     sum_s w*v[s,b,:] atomically into dout (v read once, float4 2-row).
__global__ __launch_bounds__(256, 3) void fused_gemm_tanh_logit(
    const float* __restrict__ kin, const uint16_t* __restrict__ wkb,
    const float* __restrict__ hq, const float* __restrict__ Wo,
    float* __restrict__ wlog, const float* __restrict__ vin,
    float* __restrict__ dout) {
  __shared__ float lpart[256];
  __shared__ float sw[64];

  const int tid = threadIdx.x;
  const int sc = blockIdx.x; // s-chunk (64 rows)
  const int b = blockIdx.y;
  const int wid = tid >> 6;
  const int lane = tid & 63;
  const int l15 = lane & 15;
  const int lg = lane >> 4;

  float hqv[4], wov[4];
#pragma unroll
  for (int ni = 0; ni < 4; ++ni) {
    const int n = wid * 64 + ni * 16 + l15;
    hqv[ni] = hq[b * Hh + n];
    wov[ni] = Wo[n];
  }

  floatx4 acc[4][4];
#pragma unroll
  for (int mi = 0; mi < 4; ++mi)
#pragma unroll
    for (int ni = 0; ni < 4; ++ni) acc[mi][ni] = (floatx4){0.f, 0.f, 0.f, 0.f};

  // A fragment row pointers: row mi*16+l15, k base lg*8
  const float* ap0 = kin + ((size_t)((sc * 64 + 0 * 16 + l15) * Bb) + b) * Kk + lg * 8;
  const float* ap1 = kin + ((size_t)((sc * 64 + 1 * 16 + l15) * Bb) + b) * Kk + lg * 8;
  const float* ap2 = kin + ((size_t)((sc * 64 + 2 * 16 + l15) * Bb) + b) * Kk + lg * 8;
  const float* ap3 = kin + ((size_t)((sc * 64 + 3 * 16 + l15) * Bb) + b) * Kk + lg * 8;

  // B per-lane base in frag-major wkb: frag (ks,ni) at + ks*8192 + ni*128
  const uint16_t* bp = wkb + ((size_t)(lg * 256 + wid * 64 + l15)) * 8;

  // ---------------- barrier-free 16-stage K-loop ----------------
#pragma unroll 4
  for (int ks = 0; ks < 16; ++ks) {
    bf16x8 bfr[4];
#pragma unroll
    for (int ni = 0; ni < 4; ++ni)
      bfr[ni] = *(const bf16x8*)(bp + (size_t)ks * 8192 + ni * 128);
    bf16x8 af[4];
    {
      float4 p0, p1;
      uint4 w;
      p0 = *(const float4*)(ap0 + ks * 32);
      p1 = *(const float4*)(ap0 + ks * 32 + 4);
      w.x = packbf(p0.x, p0.y); w.y = packbf(p0.z, p0.w);
      w.z = packbf(p1.x, p1.y); w.w = packbf(p1.z, p1.w);
      af[0] = __builtin_bit_cast(bf16x8, w);
      p0 = *(const float4*)(ap1 + ks * 32);
      p1 = *(const float4*)(ap1 + ks * 32 + 4);
      w.x = packbf(p0.x, p0.y); w.y = packbf(p0.z, p0.w);
      w.z = packbf(p1.x, p1.y); w.w = packbf(p1.z, p1.w);
      af[1] = __builtin_bit_cast(bf16x8, w);
      p0 = *(const float4*)(ap2 + ks * 32);
      p1 = *(const float4*)(ap2 + ks * 32 + 4);
      w.x = packbf(p0.x, p0.y); w.y = packbf(p0.z, p0.w);
      w.z = packbf(p1.x, p1.y); w.w = packbf(p1.z, p1.w);
      af[2] = __builtin_bit_cast(bf16x8, w);
      p0 = *(const float4*)(ap3 + ks * 32);
      p1 = *(const float4*)(ap3 + ks * 32 + 4);
      w.x = packbf(p0.x, p0.y); w.y = packbf(p0.z, p0.w);
      w.z = packbf(p1.x, p1.y); w.w = packbf(p1.z, p1.w);
      af[3] = __builtin_bit_cast(bf16x8, w);
    }
#pragma unroll
    for (int mi = 0; mi < 4; ++mi)
#pragma unroll
      for (int ni = 0; ni < 4; ++ni)
        acc[mi][ni] = __builtin_amdgcn_mfma_f32_16x16x32_bf16(
            af[mi], bfr[ni], acc[mi][ni], 0, 0, 0);
  }

  // epilogue: tanh + dot with Wo; C/D layout: col = lane&15, row = lg*4 + reg
#pragma unroll
  for (int mi = 0; mi < 4; ++mi) {
#pragma unroll
    for (int r = 0; r < 4; ++r) {
      float sum = 0.f;
#pragma unroll
      for (int ni = 0; ni < 4; ++ni) {
        const float x = acc[mi][ni][r] + hqv[ni];
        const float e = __expf(2.f * x);
        const float th = 1.f - 2.f * __builtin_amdgcn_rcpf(e + 1.f);
        sum = fmaf(th, wov[ni], sum);
      }
      sum += __shfl_xor(sum, 1, 64);
      sum += __shfl_xor(sum, 2, 64);
      sum += __shfl_xor(sum, 4, 64);
      sum += __shfl_xor(sum, 8, 64);
      if (l15 == 0) lpart[wid * 64 + mi * 16 + lg * 4 + r] = sum;
    }
  }
  __syncthreads();
  if (tid < 64) {
    const float lv = lpart[tid] + lpart[64 + tid] + lpart[128 + tid] + lpart[192 + tid];
    const float w = __expf(lv); // |lv| <= 25.6 -> fp32-safe; max-sub redundant
    wlog[b * Ss + sc * 64 + tid] = w;
    sw[tid] = w;
  }
  __syncthreads();

  // fused weighted-V accumulation: out[b][:] += sum_{s in chunk} w_s * v[s][b][:]
  const int c4 = tid & 127; // float4 column
  const int sh = tid >> 7;  // 0/1: s parity
  float4 a4 = {0.f, 0.f, 0.f, 0.f};
#pragma unroll 8
  for (int i = 0; i < 32; ++i) {
    const int s = sh + 2 * i;
    const float4 vv = *(const float4*)(vin + ((size_t)((sc * 64 + s) * Bb) + b) * Vv + c4 * 4);
    const float pw = sw[s];
    a4.x = fmaf(pw, vv.x, a4.x);
    a4.y = fmaf(pw, vv.y, a4.y);
    a4.z = fmaf(pw, vv.z, a4.z);
    a4.w = fmaf(pw, vv.w, a4.w);
  }
  float* o = dout + b * Vv + c4 * 4;
  atomicAdd(o + 0, a4.x);
  atomicAdd(o + 1, a4.y);
  atomicAdd(o + 2, a4.z);
  atomicAdd(o + 3, a4.w);
}

// ---------------------------------------------------------------------------
// finalize: per b, D = sum_s w; p = w/D; out *= 1/D.
__global__ void finalize(const float* __restrict__ wlog, float* __restrict__ dout) {
  const int b = blockIdx.x;
  const int t = threadIdx.x; // 256
  const int wid = t >> 6, lane = t & 63;
  __shared__ float red[4];
  const float4* wp = (const float4*)(wlog + b * Ss);
  const float4 x0 = wp[t * 2], x1 = wp[t * 2 + 1];
  float s = ((x0.x + x0.y) + (x0.z + x0.w)) + ((x1.x + x1.y) + (x1.z + x1.w));
#pragma unroll
  for (int off = 1; off < 64; off <<= 1) s += __shfl_xor(s, off, 64);
  if (lane == 0) red[wid] = s;
  __syncthreads();
  s = (red[0] + red[1]) + (red[2] + red[3]);
  const float inv = 1.f / s;
  float4 p0, p1;
  p0.x = x0.x * inv; p0.y = x0.y * inv; p0.z = x0.z * inv; p0.w = x0.w * inv;
  p1.x = x1.x * inv; p1.y = x1.y * inv; p1.z = x1.z * inv; p1.w = x1.w * inv;
  float4* pout = (float4*)(dout + OUTP + b * Ss);
  pout[t * 2] = p0;
  pout[t * 2 + 1] = p1;
  // scale out-section (atomic-accumulated U) by 1/D
  float2* op = (float2*)(dout + b * Vv + t * 2);
  float2 ov = *op;
  ov.x *= inv;
  ov.y *= inv;
  *op = ov;
}

// ---------------------------------------------------------------------------
extern "C" void kernel_launch(void* const* d_in, const int* in_sizes, int n_in,
                              void* d_out, int out_size, void* d_ws, size_t ws_size,
                              hipStream_t stream) {
  const float* q  = (const float*)d_in[0];
  const float* k  = (const float*)d_in[1];
  const float* v  = (const float*)d_in[2];
  const float* Wk = (const float*)d_in[3];
  const float* bk = (const float*)d_in[4];
  const float* Wq = (const float*)d_in[5];
  const float* bq = (const float*)d_in[6];
  const float* Wo = (const float*)d_in[7];

  float* out = (float*)d_out;
  char* ws = (char*)d_ws;
  float* hq = (float*)(ws + WS_HQ);
  uint16_t* wkb = (uint16_t*)(ws + WS_WKB);
  float* wlog = (float*)(ws + WS_LOGIT);

  prep<<<dim3(385), dim3(256), 0, stream>>>(q, Wq, bq, bk, Wk, wkb, hq, out);
  fused_gemm_tanh_logit<<<dim3(Ss / 64, Bb), dim3(256), 0, stream>>>(k, wkb, hq, Wo, wlog, v, out);
  finalize<<<dim3(Bb), dim3(256), 0, stream>>>(wlog, out);
}

// Round 8
// 316.154 us; speedup vs baseline: 1.2604x; 1.2604x over previous
//
#include <hip/hip_runtime.h>
#include <stdint.h>

// Problem constants: B=32, S=2048, K=512, V=512, H=256
#define Bb 32
#define Ss 2048
#define Kk 512
#define Vv 512
#define Hh 256

#define OUTP (Bb * Vv) // offset of p within d_out (out [1,B,V] then p [B,S])

// ws layout (bytes):
//   [0,       32768)   hq[B][H] fp32 (= q@Wq^T + bq + bk)
//   [32768,  294912)   Wk bf16, frag-major: [stage32][grp=lg][h][8]
//   [294912, 557056)   w[B][S] fp32 (unnormalized exp(logit))
#define WS_HQ 0
#define WS_WKB 32768
#define WS_LOGIT 294912

typedef float floatx4 __attribute__((ext_vector_type(4)));
typedef __bf16 bf16x8 __attribute__((ext_vector_type(8)));

__device__ __forceinline__ uint32_t bfround(float f) {
  uint32_t u = __float_as_uint(f);
  return (u + 0x7fffu + ((u >> 16) & 1u)) >> 16;
}
__device__ __forceinline__ uint32_t packbf(float lo, float hi) {
  return bfround(lo) | (bfround(hi) << 16);
}

// async global->LDS, 16B per lane; lds dest is wave-uniform base + lane*16
__device__ __forceinline__ void gload_lds16(const uint16_t* g, uint16_t* l) {
  __builtin_amdgcn_global_load_lds((const __attribute__((address_space(1))) void*)g,
                                   (__attribute__((address_space(3))) void*)l, 16, 0, 0);
}

// ---------------------------------------------------------------------------
// prep (merged): blocks [0,128): retile Wk fp32 -> bf16 frag-major (BK=32).
//                blocks [128,384): hq[b][h] = q[b]·Wq[h] + bq[h] + bk[h]
//                block 384: zero the out-section of d_out (gemm atomics land there)
__global__ void prep(const float* __restrict__ q, const float* __restrict__ Wq,
                     const float* __restrict__ bq, const float* __restrict__ bk,
                     const float* __restrict__ Wk, uint16_t* __restrict__ wkb,
                     float* __restrict__ hq, float* __restrict__ dout) {
  __shared__ float red[256];
  const int bx = blockIdx.x;
  const int t = threadIdx.x;
  if (bx < 128) {
    const int i = (bx * 256 + t) * 4; // 4 consecutive k of one h row
    float4 w = *(const float4*)(Wk + i);
    const int h = i >> 9;
    const int k = i & 511;
    const int stage = k >> 5;      // 16 stages of K=32
    const int grp = (k & 31) >> 3; // lg group 0..3
    const int j = k & 7;           // 0 or 4 here
    uint2 pk;
    pk.x = packbf(w.x, w.y);
    pk.y = packbf(w.z, w.w);
    *(uint2*)(wkb + stage * 8192 + (grp * 256 + h) * 8 + j) = pk;
  } else if (bx < 384) {
    const int idx = bx - 128; // 0..255
    const int b = idx >> 3;
    const int hc = idx & 7;
    const int h_in = t & 31;
    const int kp = t >> 5; // 8-way K split
    const int h = hc * 32 + h_in;
    const float4* qp = (const float4*)(q + b * Kk + kp * 64);
    const float4* wp = (const float4*)(Wq + h * Kk + kp * 64);
    float acc = 0.f;
#pragma unroll
    for (int i = 0; i < 16; ++i) {
      float4 qa = qp[i], wa = wp[i];
      acc = fmaf(qa.x, wa.x, acc);
      acc = fmaf(qa.y, wa.y, acc);
      acc = fmaf(qa.z, wa.z, acc);
      acc = fmaf(qa.w, wa.w, acc);
    }
    red[t] = acc;
    __syncthreads();
    if (t < 32) {
      float s = 0.f;
#pragma unroll
      for (int kp2 = 0; kp2 < 8; ++kp2) s += red[kp2 * 32 + t];
      const int hh = hc * 32 + t;
      hq[b * Hh + hh] = s + bq[hh] + bk[hh];
    }
  } else {
    // zero out-section: Bb*Vv = 16384 floats = 4096 float4
    float4 z = {0.f, 0.f, 0.f, 0.f};
    float4* o = (float4*)dout + t;
#pragma unroll
    for (int i = 0; i < 16; ++i) o[i * 256] = z;
  }
}

// ---------------------------------------------------------------------------
// Main GEMM+tanh+logit+exp + fused weighted-V accumulation.
// Block (sc, b): 64 consecutive s for one batch b. BM=64, BN=256, BK=32,
// 16 stages. R6 structure, but with COUNTED-vmcnt raw barriers (T3/T4, m201):
//   - per stage: issue B gload_lds(ks+1) -> A cvt+ds_write(ks+1) ->
//     issue A global prefetch(ks+2) -> ds_read+16 MFMA ->
//     s_waitcnt vmcnt(2) lgkmcnt(0) + s_barrier.
//     vmcnt(2) drains B(ks+1) (needed next stage) but leaves the two A(ks+2)
//     HBM loads IN FLIGHT across the barrier — they get ~2 stages of compute
//     to complete instead of being drained at their issue stage.
//   - prologue ends with a full drain so in-loop vmcnt hand-counts are exact
//     (hqv/wov loads retired; per-wave in-loop vm ops: 4 gload_lds + 2 A loads).
//   - stage 14 drains vmcnt(0) (no A(16) exists); stage 15 has no barrier.
//   - epilogue unchanged from R6 (vanilla __syncthreads, fused v-accum).
__global__ __launch_bounds__(256, 4) void fused_gemm_tanh_logit(
    const float* __restrict__ kin, const uint16_t* __restrict__ wkb,
    const float* __restrict__ hq, const float* __restrict__ Wo,
    float* __restrict__ wlog, const float* __restrict__ vin,
    float* __restrict__ dout) {
  __shared__ __align__(16) uint16_t lA[2][2048]; // [buf][(grp*64+row)*8+j]
  __shared__ __align__(16) uint16_t lB[2][8192]; // [buf][(grp*256+n)*8+j]
  __shared__ float lpart[256];
  __shared__ float sw[64];

  const int tid = threadIdx.x;
  const int sc = blockIdx.x; // s-chunk (64 rows)
  const int b = blockIdx.y;
  const int wid = tid >> 6;
  const int lane = tid & 63;
  const int l15 = lane & 15;
  const int lg = lane >> 4;

  float hqv[4], wov[4];
#pragma unroll
  for (int ni = 0; ni < 4; ++ni) {
    const int n = wid * 64 + ni * 16 + l15;
    hqv[ni] = hq[b * Hh + n];
    wov[ni] = Wo[n];
  }

  floatx4 acc[4][4];
#pragma unroll
  for (int mi = 0; mi < 4; ++mi)
#pragma unroll
    for (int ni = 0; ni < 4; ++ni) acc[mi][ni] = (floatx4){0.f, 0.f, 0.f, 0.f};

  // ---- A staging: thread t covers 8 floats of row (t>>2), part (t&3)
  const int arow = tid >> 2; // s-offset 0..63
  const int apart = tid & 3;
  const float* aptr = kin + ((size_t)((sc * 64 + arow) * Bb) + b) * Kk + apart * 8;
  uint16_t* awr = &lA[0][0] + (apart * 64 + arow) * 8;

  // ---- B staging (linear copy; wkb layout == lB layout)
  const uint16_t* bsrc = wkb + (wid * 4) * 512 + lane * 8;
  uint16_t* bdst = &lB[0][0] + (wid * 4) * 512;

  float4 av0, av1;

  // ---------------- prologue ----------------
#pragma unroll
  for (int it = 0; it < 4; ++it) gload_lds16(bsrc + it * 512, bdst + it * 512);
  {
    float4 a0 = *(const float4*)(aptr);
    float4 a1 = *(const float4*)(aptr + 4);
    av0 = *(const float4*)(aptr + 32);
    av1 = *(const float4*)(aptr + 36);
    uint4 w;
    w.x = packbf(a0.x, a0.y);
    w.y = packbf(a0.z, a0.w);
    w.z = packbf(a1.x, a1.y);
    w.w = packbf(a1.z, a1.w);
    *(uint4*)awr = w;
  }
  // full drain once: retires hqv/wov/A0/A1/B0 so in-loop vmcnt counts are exact
  asm volatile("s_waitcnt vmcnt(0) lgkmcnt(0)" ::: "memory");
  __builtin_amdgcn_sched_barrier(0);
  __builtin_amdgcn_s_barrier();
  __builtin_amdgcn_sched_barrier(0);

  // ---------------- 16-stage pipeline, counted-vmcnt barriers ----------------
#pragma unroll
  for (int ks = 0; ks < 16; ++ks) {
    const int cur = ks & 1, nxt = cur ^ 1;
    // 1. B for stage ks+1 (async into LDS buf nxt; 4 vm ops)
    if (ks < 15) {
#pragma unroll
      for (int it = 0; it < 4; ++it)
        gload_lds16(bsrc + (ks + 1) * 8192 + it * 512, bdst + nxt * 8192 + it * 512);
    }
    // 2. A cvt+write for stage ks+1 (av complete: loaded >=1 stage ago)
    if (ks < 15) {
      uint4 w;
      w.x = packbf(av0.x, av0.y);
      w.y = packbf(av0.z, av0.w);
      w.z = packbf(av1.x, av1.y);
      w.w = packbf(av1.z, av1.w);
      *(uint4*)(awr + nxt * 2048) = w;
    }
    // 3. A global prefetch for stage ks+2 (2 vm ops; stay in flight across
    //    this stage's barrier — consumed at stage ks+1's cvt)
    if (ks < 14) {
      av0 = *(const float4*)(aptr + (ks + 2) * 32);
      av1 = *(const float4*)(aptr + (ks + 2) * 32 + 4);
    }
    // 4. compute stage ks: 16 MFMA (compiler inserts exact lgkm waits)
    {
      bf16x8 af[4], bfr[4];
#pragma unroll
      for (int mi = 0; mi < 4; ++mi)
        af[mi] = *(const bf16x8*)&lA[cur][(lg * 64 + mi * 16 + l15) * 8];
#pragma unroll
      for (int ni = 0; ni < 4; ++ni)
        bfr[ni] = *(const bf16x8*)&lB[cur][(lg * 256 + wid * 64 + ni * 16 + l15) * 8];
#pragma unroll
      for (int mi = 0; mi < 4; ++mi)
#pragma unroll
        for (int ni = 0; ni < 4; ++ni)
          acc[mi][ni] = __builtin_amdgcn_mfma_f32_16x16x32_bf16(
              af[mi], bfr[ni], acc[mi][ni], 0, 0, 0);
    }
    // 5. stage barrier: drain B(ks+1) + own ds ops; A(ks+2) stays outstanding
    if (ks < 15) {
      if (ks == 14)
        asm volatile("s_waitcnt vmcnt(0) lgkmcnt(0)" ::: "memory");
      else
        asm volatile("s_waitcnt vmcnt(2) lgkmcnt(0)" ::: "memory");
      __builtin_amdgcn_sched_barrier(0);
      __builtin_amdgcn_s_barrier();
      __builtin_amdgcn_sched_barrier(0);
    }
  }

  // epilogue: tanh + dot with Wo; C/D layout: col = lane&15, row = lg*4 + reg
#pragma unroll
  for (int mi = 0; mi < 4; ++mi) {
#pragma unroll
    for (int r = 0; r < 4; ++r) {
      float sum = 0.f;
#pragma unroll
      for (int ni = 0; ni < 4; ++ni) {
        const float x = acc[mi][ni][r] + hqv[ni];
        const float e = __expf(2.f * x);
        const float th = 1.f - 2.f * __builtin_amdgcn_rcpf(e + 1.f);
        sum = fmaf(th, wov[ni], sum);
      }
      sum += __shfl_xor(sum, 1, 64);
      sum += __shfl_xor(sum, 2, 64);
      sum += __shfl_xor(sum, 4, 64);
      sum += __shfl_xor(sum, 8, 64);
      if (l15 == 0) lpart[wid * 64 + mi * 16 + lg * 4 + r] = sum;
    }
  }
  __syncthreads();
  if (tid < 64) {
    const float lv = lpart[tid] + lpart[64 + tid] + lpart[128 + tid] + lpart[192 + tid];
    const float w = __expf(lv); // |lv| <= 25.6 -> fp32-safe; max-sub redundant
    wlog[b * Ss + sc * 64 + tid] = w;
    sw[tid] = w;
  }
  __syncthreads();

  // fused weighted-V accumulation: out[b][:] += sum_{s in chunk} w_s * v[s][b][:]
  const int c4 = tid & 127; // float4 column
  const int sh = tid >> 7;  // 0/1: s parity
  float4 a4 = {0.f, 0.f, 0.f, 0.f};
#pragma unroll 8
  for (int i = 0; i < 32; ++i) {
    const int s = sh + 2 * i;
    const float4 vv = *(const float4*)(vin + ((size_t)((sc * 64 + s) * Bb) + b) * Vv + c4 * 4);
    const float pw = sw[s];
    a4.x = fmaf(pw, vv.x, a4.x);
    a4.y = fmaf(pw, vv.y, a4.y);
    a4.z = fmaf(pw, vv.z, a4.z);
    a4.w = fmaf(pw, vv.w, a4.w);
  }
  float* o = dout + b * Vv + c4 * 4;
  atomicAdd(o + 0, a4.x);
  atomicAdd(o + 1, a4.y);
  atomicAdd(o + 2, a4.z);
  atomicAdd(o + 3, a4.w);
}

// ---------------------------------------------------------------------------
// finalize: per b, D = sum_s w; p = w/D; out *= 1/D.
__global__ void finalize(const float* __restrict__ wlog, float* __restrict__ dout) {
  const int b = blockIdx.x;
  const int t = threadIdx.x; // 256
  const int wid = t >> 6, lane = t & 63;
  __shared__ float red[4];
  const float4* wp = (const float4*)(wlog + b * Ss);
  const float4 x0 = wp[t * 2], x1 = wp[t * 2 + 1];
  float s = ((x0.x + x0.y) + (x0.z + x0.w)) + ((x1.x + x1.y) + (x1.z + x1.w));
#pragma unroll
  for (int off = 1; off < 64; off <<= 1) s += __shfl_xor(s, off, 64);
  if (lane == 0) red[wid] = s;
  __syncthreads();
  s = (red[0] + red[1]) + (red[2] + red[3]);
  const float inv = 1.f / s;
  float4 p0, p1;
  p0.x = x0.x * inv; p0.y = x0.y * inv; p0.z = x0.z * inv; p0.w = x0.w * inv;
  p1.x = x1.x * inv; p1.y = x1.y * inv; p1.z = x1.z * inv; p1.w = x1.w * inv;
  float4* pout = (float4*)(dout + OUTP + b * Ss);
  pout[t * 2] = p0;
  pout[t * 2 + 1] = p1;
  // scale out-section (atomic-accumulated U) by 1/D
  float2* op = (float2*)(dout + b * Vv + t * 2);
  float2 ov = *op;
  ov.x *= inv;
  ov.y *= inv;
  *op = ov;
}

// ---------------------------------------------------------------------------
extern "C" void kernel_launch(void* const* d_in, const int* in_sizes, int n_in,
                              void* d_out, int out_size, void* d_ws, size_t ws_size,
                              hipStream_t stream) {
  const float* q  = (const float*)d_in[0];
  const float* k  = (const float*)d_in[1];
  const float* v  = (const float*)d_in[2];
  const float* Wk = (const float*)d_in[3];
  const float* bk = (const float*)d_in[4];
  const float* Wq = (const float*)d_in[5];
  const float* bq = (const float*)d_in[6];
  const float* Wo = (const float*)d_in[7];

  float* out = (float*)d_out;
  char* ws = (char*)d_ws;
  float* hq = (float*)(ws + WS_HQ);
  uint16_t* wkb = (uint16_t*)(ws + WS_WKB);
  float* wlog = (float*)(ws + WS_LOGIT);

  prep<<<dim3(385), dim3(256), 0, stream>>>(q, Wq, bq, bk, Wk, wkb, hq, out);
  fused_gemm_tanh_logit<<<dim3(Ss / 64, Bb), dim3(256), 0, stream>>>(k, wkb, hq, Wo, wlog, v, out);
  finalize<<<dim3(Bb), dim3(256), 0, stream>>>(wlog, out);
}

// Round 9
// 314.587 us; speedup vs baseline: 1.2667x; 1.0050x over previous
//
#include <hip/hip_runtime.h>
#include <stdint.h>

// Problem constants: B=32, S=2048, K=512, V=512, H=256
#define Bb 32
#define Ss 2048
#define Kk 512
#define Vv 512
#define Hh 256

#define OUTP (Bb * Vv) // offset of p within d_out (out [1,B,V] then p [B,S])

// ws layout (bytes):
//   [0,       32768)   hq[B][H] fp32 (= q@Wq^T + bq + bk)
//   [32768,  294912)   Wk bf16, frag-major: [stage32][grp=lg][h][8]
//   [294912, 557056)   w[B][S] fp32 (unnormalized exp(logit))
#define WS_HQ 0
#define WS_WKB 32768
#define WS_LOGIT 294912

typedef float floatx4 __attribute__((ext_vector_type(4)));
typedef __bf16 bf16x8 __attribute__((ext_vector_type(8)));

__device__ __forceinline__ uint32_t bfround(float f) {
  uint32_t u = __float_as_uint(f);
  return (u + 0x7fffu + ((u >> 16) & 1u)) >> 16;
}
__device__ __forceinline__ uint32_t packbf(float lo, float hi) {
  return bfround(lo) | (bfround(hi) << 16);
}

// ---------------------------------------------------------------------------
// prep (merged): blocks [0,128): retile Wk fp32 -> bf16 frag-major (BK=32).
//                blocks [128,384): hq[b][h] = q[b]·Wq[h] + bq[h] + bk[h]
//                block 384: zero the out-section of d_out (gemm atomics land there)
__global__ void prep(const float* __restrict__ q, const float* __restrict__ Wq,
                     const float* __restrict__ bq, const float* __restrict__ bk,
                     const float* __restrict__ Wk, uint16_t* __restrict__ wkb,
                     float* __restrict__ hq, float* __restrict__ dout) {
  __shared__ float red[256];
  const int bx = blockIdx.x;
  const int t = threadIdx.x;
  if (bx < 128) {
    const int i = (bx * 256 + t) * 4; // 4 consecutive k of one h row
    float4 w = *(const float4*)(Wk + i);
    const int h = i >> 9;
    const int k = i & 511;
    const int stage = k >> 5;      // 16 stages of K=32
    const int grp = (k & 31) >> 3; // lg group 0..3
    const int j = k & 7;           // 0 or 4 here
    uint2 pk;
    pk.x = packbf(w.x, w.y);
    pk.y = packbf(w.z, w.w);
    *(uint2*)(wkb + stage * 8192 + (grp * 256 + h) * 8 + j) = pk;
  } else if (bx < 384) {
    const int idx = bx - 128; // 0..255
    const int b = idx >> 3;
    const int hc = idx & 7;
    const int h_in = t & 31;
    const int kp = t >> 5; // 8-way K split
    const int h = hc * 32 + h_in;
    const float4* qp = (const float4*)(q + b * Kk + kp * 64);
    const float4* wp = (const float4*)(Wq + h * Kk + kp * 64);
    float acc = 0.f;
#pragma unroll
    for (int i = 0; i < 16; ++i) {
      float4 qa = qp[i], wa = wp[i];
      acc = fmaf(qa.x, wa.x, acc);
      acc = fmaf(qa.y, wa.y, acc);
      acc = fmaf(qa.z, wa.z, acc);
      acc = fmaf(qa.w, wa.w, acc);
    }
    red[t] = acc;
    __syncthreads();
    if (t < 32) {
      float s = 0.f;
#pragma unroll
      for (int kp2 = 0; kp2 < 8; ++kp2) s += red[kp2 * 32 + t];
      const int hh = hc * 32 + t;
      hq[b * Hh + hh] = s + bq[hh] + bk[hh];
    }
  } else {
    // zero out-section: Bb*Vv = 16384 floats = 4096 float4
    float4 z = {0.f, 0.f, 0.f, 0.f};
    float4* o = (float4*)dout + t;
#pragma unroll
    for (int i = 0; i < 16; ++i) o[i * 256] = z;
  }
}

// ---------------------------------------------------------------------------
// Main GEMM+tanh+logit+exp + fused weighted-V accumulation.
// Block (sc, b): 64 consecutive s for one batch b. BM=64, BN=256 (full H).
// KEY FIX vs R6: A rows for fixed b are 64KB-strided in k[S,B,K]; R6's
// per-stage staging issued 64B islands at 64KB stride (16 scattered
// transactions/instr -> ~1.4TB/s). Now we stage the WHOLE 64x512 A-tile ONCE:
// per wave 16 rows x 2KB, each row read as 2 instructions of 64 lanes x 16B
// = 1KB CONTIGUOUS, sequential rows -> 2KB DRAM bursts. Then the K-loop is
// BARRIER-FREE: A from LDS (read-only after one barrier), B reg-double-
// buffered from L2-hot frag-major wkb. No vmcnt drains anywhere in the loop.
//   - LDS = 64KB exactly (A-tile); lpart/sw overlay dead lA behind a barrier.
//   - Epilogue: tanh + Wo-dot -> w = exp(logit) (|logit|<=25.6, max-sub
//     redundant); fused sum_s w*v atomics into dout (v read once).
__global__ __launch_bounds__(256, 2) void fused_gemm_tanh_logit(
    const float* __restrict__ kin, const uint16_t* __restrict__ wkb,
    const float* __restrict__ hq, const float* __restrict__ Wo,
    float* __restrict__ wlog, const float* __restrict__ vin,
    float* __restrict__ dout) {
  // A-tile, frag-major: [kgrp=k/8 (64)][row (64)][8 bf16] = 65536 B
  __shared__ __align__(16) uint16_t lA[64 * 64 * 8];

  const int tid = threadIdx.x;
  const int sc = blockIdx.x; // s-chunk (64 rows)
  const int b = blockIdx.y;
  const int wid = tid >> 6;
  const int lane = tid & 63;
  const int l15 = lane & 15;
  const int lg = lane >> 4;

  float hqv[4], wov[4];
#pragma unroll
  for (int ni = 0; ni < 4; ++ni) {
    const int n = wid * 64 + ni * 16 + l15;
    hqv[ni] = hq[b * Hh + n];
    wov[ni] = Wo[n];
  }

  floatx4 acc[4][4];
#pragma unroll
  for (int mi = 0; mi < 4; ++mi)
#pragma unroll
    for (int ni = 0; ni < 4; ++ni) acc[mi][ni] = (floatx4){0.f, 0.f, 0.f, 0.f};

  // ---------------- A-tile staging: wave wid stages rows wid*16..+15 ----------
  // Per row r, half h: lanes read float4 at k = h*256 + lane*4 (1KB contiguous
  // per instruction). Pack 4 floats -> uint2, ds_write_b64 at
  // kgrp = h*32 + (lane>>1), byte = kgrp*1024 + r*16 + (lane&1)*8.
  {
    const float* rowbase = kin + ((size_t)((sc * 64 + wid * 16) * Bb) + b) * Kk;
    uint16_t* wr0 = &lA[0] + (size_t)(lane >> 1) * 512 + (lane & 1) * 4; // +r*8, +h*32*512
#pragma unroll
    for (int i = 0; i < 16; ++i) {
      const float* rp = rowbase + (size_t)i * (Bb * Kk);
      const int r = wid * 16 + i;
      float4 f0 = *(const float4*)(rp + lane * 4);         // h=0
      float4 f1 = *(const float4*)(rp + 256 + lane * 4);   // h=1
      uint2 p0, p1;
      p0.x = packbf(f0.x, f0.y); p0.y = packbf(f0.z, f0.w);
      p1.x = packbf(f1.x, f1.y); p1.y = packbf(f1.z, f1.w);
      *(uint2*)(wr0 + r * 8) = p0;
      *(uint2*)(wr0 + 32 * 512 + r * 8) = p1;
    }
  }
  // B per-lane base in frag-major wkb: frag (ks,ni) at + ks*8192 + ni*128
  const uint16_t* bp = wkb + ((size_t)(lg * 256 + wid * 64 + l15)) * 8;
  __syncthreads();

  // ---------------- barrier-free 16-stage K-loop ----------------
  // B reg-double-buffered (issued 1 stage ahead); A ds_read per stage;
  // no barriers, no vmcnt drains — waves drift freely, ILP hides L2/LDS.
  bf16x8 breg[2][4];
#pragma unroll
  for (int ni = 0; ni < 4; ++ni) breg[0][ni] = *(const bf16x8*)(bp + ni * 128);
#pragma unroll
  for (int ks = 0; ks < 16; ++ks) {
    const int cur = ks & 1, nxt = cur ^ 1;
    if (ks < 15) {
#pragma unroll
      for (int ni = 0; ni < 4; ++ni)
        breg[nxt][ni] = *(const bf16x8*)(bp + (size_t)(ks + 1) * 8192 + ni * 128);
    }
    bf16x8 af[4];
#pragma unroll
    for (int mi = 0; mi < 4; ++mi)
      af[mi] = *(const bf16x8*)&lA[((size_t)(ks * 4 + lg) * 64 + mi * 16 + l15) * 8];
#pragma unroll
    for (int mi = 0; mi < 4; ++mi)
#pragma unroll
      for (int ni = 0; ni < 4; ++ni)
        acc[mi][ni] = __builtin_amdgcn_mfma_f32_16x16x32_bf16(
            af[mi], breg[cur][ni], acc[mi][ni], 0, 0, 0);
  }

  __syncthreads(); // all waves done reading lA -> safe to overlay lpart/sw
  float* lpart = (float*)&lA[0];      // 256 floats
  float* sw = (float*)&lA[0] + 256;   // 64 floats

  // epilogue: tanh + dot with Wo; C/D layout: col = lane&15, row = lg*4 + reg
#pragma unroll
  for (int mi = 0; mi < 4; ++mi) {
#pragma unroll
    for (int r = 0; r < 4; ++r) {
      float sum = 0.f;
#pragma unroll
      for (int ni = 0; ni < 4; ++ni) {
        const float x = acc[mi][ni][r] + hqv[ni];
        const float e = __expf(2.f * x);
        const float th = 1.f - 2.f * __builtin_amdgcn_rcpf(e + 1.f);
        sum = fmaf(th, wov[ni], sum);
      }
      sum += __shfl_xor(sum, 1, 64);
      sum += __shfl_xor(sum, 2, 64);
      sum += __shfl_xor(sum, 4, 64);
      sum += __shfl_xor(sum, 8, 64);
      if (l15 == 0) lpart[wid * 64 + mi * 16 + lg * 4 + r] = sum;
    }
  }
  __syncthreads();
  if (tid < 64) {
    const float lv = lpart[tid] + lpart[64 + tid] + lpart[128 + tid] + lpart[192 + tid];
    const float w = __expf(lv); // |lv| <= 25.6 -> fp32-safe; max-sub redundant
    wlog[b * Ss + sc * 64 + tid] = w;
    sw[tid] = w;
  }
  __syncthreads();

  // fused weighted-V accumulation: out[b][:] += sum_{s in chunk} w_s * v[s][b][:]
  const int c4 = tid & 127; // float4 column
  const int sh = tid >> 7;  // 0/1: s parity
  float4 a4 = {0.f, 0.f, 0.f, 0.f};
#pragma unroll 8
  for (int i = 0; i < 32; ++i) {
    const int s = sh + 2 * i;
    const float4 vv = *(const float4*)(vin + ((size_t)((sc * 64 + s) * Bb) + b) * Vv + c4 * 4);
    const float pw = sw[s];
    a4.x = fmaf(pw, vv.x, a4.x);
    a4.y = fmaf(pw, vv.y, a4.y);
    a4.z = fmaf(pw, vv.z, a4.z);
    a4.w = fmaf(pw, vv.w, a4.w);
  }
  float* o = dout + b * Vv + c4 * 4;
  atomicAdd(o + 0, a4.x);
  atomicAdd(o + 1, a4.y);
  atomicAdd(o + 2, a4.z);
  atomicAdd(o + 3, a4.w);
}

// ---------------------------------------------------------------------------
// finalize: per b, D = sum_s w; p = w/D; out *= 1/D.
__global__ void finalize(const float* __restrict__ wlog, float* __restrict__ dout) {
  const int b = blockIdx.x;
  const int t = threadIdx.x; // 256
  const int wid = t >> 6, lane = t & 63;
  __shared__ float red[4];
  const float4* wp = (const float4*)(wlog + b * Ss);
  const float4 x0 = wp[t * 2], x1 = wp[t * 2 + 1];
  float s = ((x0.x + x0.y) + (x0.z + x0.w)) + ((x1.x + x1.y) + (x1.z + x1.w));
#pragma unroll
  for (int off = 1; off < 64; off <<= 1) s += __shfl_xor(s, off, 64);
  if (lane == 0) red[wid] = s;
  __syncthreads();
  s = (red[0] + red[1]) + (red[2] + red[3]);
  const float inv = 1.f / s;
  float4 p0, p1;
  p0.x = x0.x * inv; p0.y = x0.y * inv; p0.z = x0.z * inv; p0.w = x0.w * inv;
  p1.x = x1.x * inv; p1.y = x1.y * inv; p1.z = x1.z * inv; p1.w = x1.w * inv;
  float4* pout = (float4*)(dout + OUTP + b * Ss);
  pout[t * 2] = p0;
  pout[t * 2 + 1] = p1;
  // scale out-section (atomic-accumulated U) by 1/D
  float2* op = (float2*)(dout + b * Vv + t * 2);
  float2 ov = *op;
  ov.x *= inv;
  ov.y *= inv;
  *op = ov;
}

// ---------------------------------------------------------------------------
extern "C" void kernel_launch(void* const* d_in, const int* in_sizes, int n_in,
                              void* d_out, int out_size, void* d_ws, size_t ws_size,
                              hipStream_t stream) {
  const float* q  = (const float*)d_in[0];
  const float* k  = (const float*)d_in[1];
  const float* v  = (const float*)d_in[2];
  const float* Wk = (const float*)d_in[3];
  const float* bk = (const float*)d_in[4];
  const float* Wq = (const float*)d_in[5];
  const float* bq = (const float*)d_in[6];
  const float* Wo = (const float*)d_in[7];

  float* out = (float*)d_out;
  char* ws = (char*)d_ws;
  float* hq = (float*)(ws + WS_HQ);
  uint16_t* wkb = (uint16_t*)(ws + WS_WKB);
  float* wlog = (float*)(ws + WS_LOGIT);

  prep<<<dim3(385), dim3(256), 0, stream>>>(q, Wq, bq, bk, Wk, wkb, hq, out);
  fused_gemm_tanh_logit<<<dim3(Ss / 64, Bb), dim3(256), 0, stream>>>(k, wkb, hq, Wo, wlog, v, out);
  finalize<<<dim3(Bb), dim3(256), 0, stream>>>(wlog, out);
}